// Round 8
// baseline (407.986 us; speedup 1.0000x reference)
//
#include <hip/hip_runtime.h>
#include <stdint.h>

#define D_DIM 1024
#define T_DIM 4096
#define B_DIM 4
#define M_DIM 16384
#define NX 16777216UL
#define NW 1048576UL
#define LOG8F 2.0794415416798357f
#define CHUNK_L 64
#define NCHUNK 64
#define WARM 16
#define NT 32

typedef __attribute__((ext_vector_type(4))) float f32x4;
typedef __attribute__((ext_vector_type(8))) short bf16x8;

__device__ __forceinline__ unsigned short f2bf(float f) {
    unsigned u = __float_as_uint(f);
    u += 0x7fffu + ((u >> 16) & 1u);
    return (unsigned short)(u >> 16);
}
__device__ __forceinline__ float unp_lo(unsigned p) { return __uint_as_float(p << 16); }
__device__ __forceinline__ float unp_hi(unsigned p) { return __uint_as_float(p & 0xffff0000u); }
__device__ __forceinline__ float sigm(float x) { return 1.0f / (1.0f + __expf(-x)); }

__device__ __forceinline__ void gl_lds16(const void* g, void* l) {
    __builtin_amdgcn_global_load_lds(
        (const __attribute__((address_space(1))) void*)g,
        (__attribute__((address_space(3))) void*)l, 16, 0, 0);
}

// ---------------------------------------------------------------------------
// Kernel 0: convert x, W_r, W_i, W_x  fp32 -> bf16 (4 elems/thread)
// ---------------------------------------------------------------------------
__global__ __launch_bounds__(256) void cvt_kernel(
    const float* __restrict__ x, const float* __restrict__ Wr,
    const float* __restrict__ Wi, const float* __restrict__ Wx,
    unsigned short* __restrict__ xb, unsigned short* __restrict__ wb)
{
    size_t tid = (size_t)blockIdx.x * 256 + threadIdx.x;
    size_t i = tid * 4;
    const float* src;
    unsigned short* dst;
    size_t off;
    if (i < NX) {
        src = x; dst = xb; off = i;
    } else {
        size_t j = i - NX;
        size_t w = j >> 20;           // / NW
        off = j & (NW - 1);
        src = (w == 0) ? Wr : (w == 1 ? Wi : Wx);
        dst = wb + w * NW;
    }
    float4 v = *(const float4*)(src + off);
    ushort4 o;
    o.x = f2bf(v.x); o.y = f2bf(v.y); o.z = f2bf(v.z); o.w = f2bf(v.w);
    *(ushort4*)(dst + off) = o;
}

// ---------------------------------------------------------------------------
// Kernel 1: 3-fused GEMM + gating. B DIRECT-TO-REGISTER, A via LDS.
//   R5 measured the LDS pipe saturated: 112 KB/tile/CU (32 KB gl_lds writes
//   + 80 KB ds_reads) ~ 1320 cy vs 931 cy matrix; schedule-only changes
//   were neutral (142 us, MfmaUtil 32%). R4 proved bigger tiles spill
//   (reg cap 256/wave at 2 waves/SIMD). So: take B OFF the LDS pipe.
//   Each lane's B-fragment is 16 contiguous global bytes
//   (W[d0+wn*32+j*16+frow][k0+kgrp*8..]) -> plain global_load_dwordx4 into
//   registers, double-buffered one tile ahead. Weights' per-XCD 768 KB slice
//   is L2-resident (bid&7 = XCD map kept); a wave's 64 lanes touch
//   16 rows x 64 B = coalesced 64B segments, L1/L2-served.
//   New per-tile per-CU budget: LDS = A only (8 KB wr + 32 KB rd ~ 470 cy),
//   vmem = B ~ 750 cy, matrix 931 cy -> matrix-bound; three pipes instead
//   of one saturated one.
//   - LDS: A only, 4-deep x 8 KB = 32 KB. A XOR-swizzle kept (0 conflicts).
//   - vmcnt ledger (counts gl_lds AND B loads, 7 ops/step; asm memory
//     fences pin cross-step order): at STEP(T) top, 13 ops are newer than
//     stage(T+1), so vmcnt(7) retires it. Edges: prologue 0; STEP(0) 1;
//     STEP(30) 6; STEP(31) 0. Compiler auto-waits B-reg loads before
//     their consuming MFMAs (register deps; worst case it conservatively
//     tightens waits after the opaque asm -- perf loss only, never unsafe).
//   - regs: acc 96 + af 2x16 + bf 2x24 + addr ~30 = ~222 <= 256, no spill.
//   - audits (R6/R7): bank rotation race-free; bounds exact; barriers
//     uniform; spill would mis-time vmcnt -> pytest fail, not hang.
// ---------------------------------------------------------------------------
__global__ __launch_bounds__(512, 2) void fused_gemm(
    const unsigned short* __restrict__ xb, const unsigned short* __restrict__ wb,
    const float* __restrict__ b_r, const float* __restrict__ b_i,
    unsigned short* __restrict__ a_out, float* __restrict__ u_out)
{
    __shared__ __align__(16) unsigned short lds[4][4096];   // A only, 32 KB

    const int tid  = threadIdx.x;
    const int lane = tid & 63;
    const int wave = tid >> 6;
    const int wm = wave & 1;            // m-half (64 rows of 128)
    const int wn = wave >> 1;           // d-quarter (32 cols of 128)
    const int m0 = ((int)blockIdx.x >> 3) * 128;
    const int d0 = ((int)blockIdx.x & 7) * 128;
    const int frow = lane & 15;
    const int kgrp = lane >> 4;

    // A staging: thread -> LDS slot (row=tid>>2, cg=tid&3); global source
    // col-group inverse-swizzled so swizzled ds_read returns correct data
    const int r0 = tid >> 2;            // 0..127
    const int cgs = (tid & 3) ^ ((r0 >> 1) & 3);
    const unsigned short* srcA = xb + (size_t)(m0 + r0) * D_DIM + cgs * 8;

    // B: per-lane global base; fragment (w,j) at compile-time offsets
    const unsigned short* bbase =
        wb + (size_t)(d0 + wn * 32 + frow) * D_DIM + kgrp * 8;

    // A reader offsets (ushort units), swizzle folded in
    int offA[4];
    #pragma unroll
    for (int i = 0; i < 4; i++) {
        const int row = wm * 64 + i * 16 + frow;
        offA[i] = row * 32 + ((kgrp ^ ((row >> 1) & 3)) << 3);
    }

    f32x4 acc[3][4][2];
    #pragma unroll
    for (int w = 0; w < 3; w++)
        #pragma unroll
        for (int i = 0; i < 4; i++)
            #pragma unroll
            for (int j = 0; j < 2; j++) acc[w][i][j] = (f32x4){0.f, 0.f, 0.f, 0.f};

    auto stage = [&](int t) {                       // 1 gl_lds per tile
        gl_lds16(srcA + (t << 5), &lds[t & 3][tid * 8]);
    };

#define LOADB(T, BF)                                                          \
    _Pragma("unroll")                                                         \
    for (int w = 0; w < 3; w++)                                               \
        _Pragma("unroll")                                                     \
        for (int j = 0; j < 2; j++)                                           \
            BF[w][j] = *(const bf16x8*)(bbase + (size_t)w * NW +              \
                                        j * 16 * D_DIM + (T) * 32);

    // double-buffered fragments (explicit names -- rule 20: static indexing)
    bf16x8 af_a[4], af_b[4], bf_a[3][2], bf_b[3][2];

    stage(0); stage(1); stage(2);
    LOADB(0, bf_a);
    asm volatile("s_waitcnt vmcnt(0)" ::: "memory");   // prologue: full drain
    __builtin_amdgcn_s_barrier();
    asm volatile("" ::: "memory");
    #pragma unroll
    for (int i = 0; i < 4; i++) af_a[i] = *(const bf16x8*)&lds[0][offA[i]];

// STEP(T): vmcnt(VM) retires A-stage(T+1) (it always has >= VM
// guaranteed-newer vmem ops, so "<= VM outstanding" forces it done).
// Barrier publishes LDS bank (T+1). Then: issue A-stage(T+3), global-load
// B(T+1) frags into the NXT bank, ds_read A(T+1) into the NXT bank, and
// run tile T's 24 MFMAs from the CUR bank.
#define STEP(T, AFC, BFC, AFN, BFN, VM)                                       \
    {                                                                         \
        asm volatile("s_waitcnt vmcnt(" #VM ")" ::: "memory");                \
        __builtin_amdgcn_s_barrier();                                         \
        asm volatile("" ::: "memory");                                        \
        if ((T) + 3 < NT) stage((T) + 3);                                     \
        if ((T) + 1 < NT) {                                                   \
            LOADB((T) + 1, BFN);                                              \
            const unsigned short* nb = lds[((T) + 1) & 3];                    \
            _Pragma("unroll")                                                 \
            for (int i = 0; i < 4; i++)                                       \
                AFN[i] = *(const bf16x8*)&nb[offA[i]];                        \
        }                                                                     \
        __builtin_amdgcn_s_setprio(1);                                        \
        _Pragma("unroll")                                                     \
        for (int w = 0; w < 3; w++)                                           \
            _Pragma("unroll")                                                 \
            for (int i = 0; i < 4; i++)                                       \
                _Pragma("unroll")                                             \
                for (int j = 0; j < 2; j++)                                   \
                    acc[w][i][j] = __builtin_amdgcn_mfma_f32_16x16x32_bf16(   \
                        AFC[i], BFC[w][j], acc[w][i][j], 0, 0, 0);            \
        __builtin_amdgcn_s_setprio(0);                                        \
    }

    STEP(0, af_a, bf_a, af_b, bf_b, 1);
    for (int t = 1; t < 29; t += 2) {
        STEP(t,     af_b, bf_b, af_a, bf_a, 7);
        STEP(t + 1, af_a, bf_a, af_b, bf_b, 7);
    }
    STEP(29, af_b, bf_b, af_a, bf_a, 7);
    STEP(30, af_a, bf_a, af_b, bf_b, 6);
    STEP(31, af_b, bf_b, af_a, bf_a, 0);
#undef STEP
#undef LOADB

    // Epilogue. C/D layout: col(d) = lane&15, row(m) = (lane>>4)*4 + r.
    const int mb = m0 + wm * 64 + kgrp * 4;
    const int db = d0 + wn * 32 + frow;
    #pragma unroll
    for (int j = 0; j < 2; j++) {
        const int d = db + j * 16;
        const float br = b_r[d];
        const float bi = b_i[d];
        #pragma unroll
        for (int i = 0; i < 4; i++) {
            const int m = mb + i * 16;
            #pragma unroll
            for (int r = 0; r < 4; r++) {
                const size_t idx = (size_t)(m + r) * D_DIM + d;
                float rg = sigm(acc[0][i][j][r] + br);
                // exp(-softplus(z)) == sigmoid(-z);  a in (0.11, 0.5)
                float a = sigm(-LOG8F * rg);
                a_out[idx] = f2bf(a);
                float g = sqrtf(fmaxf(1.0f - a * a, 1e-6f));
                u_out[idx] = g * sigm(acc[1][i][j][r] + bi) * acc[2][i][j][r];
            }
        }
    }
}

// ---------------------------------------------------------------------------
// Kernel 2: chunk-start h via 16-step warm-up (a <= 0.5 => decay >= 1 bit/step,
// so truncation error <= 2^-16 * |h|). 2 d-chains per thread (float2 loads).
// Must stay a separate launch: apply overwrites u in place, warm reads u.
// ---------------------------------------------------------------------------
__global__ __launch_bounds__(256) void scan_warm(
    const unsigned short* __restrict__ a, const float* __restrict__ u,
    const float* __restrict__ h0, float* __restrict__ hstart)
{
    int tid = blockIdx.x * 256 + threadIdx.x;   // (b*NCHUNK + c)*512 + d2
    int d = (tid & 511) << 1;
    int bc = tid >> 9;
    int b = bc >> 6;
    int c = bc & (NCHUNK - 1);
    float hx, hy;
    if (c == 0) {
        float2 h = *(const float2*)(h0 + b * D_DIM + d);
        hx = h.x; hy = h.y;
    } else {
        hx = 0.0f; hy = 0.0f;
        size_t base = ((size_t)b * T_DIM + (size_t)c * CHUNK_L - WARM) * D_DIM + d;
        #pragma unroll 4
        for (int t = 0; t < WARM; t++) {
            size_t idx = base + (size_t)t * D_DIM;
            unsigned ap = *(const unsigned*)(a + idx);
            float2 uv = *(const float2*)(u + idx);
            hx = unp_lo(ap) * hx + uv.x;
            hy = unp_hi(ap) * hy + uv.y;
        }
    }
    *(float2*)(hstart + bc * D_DIM + d) = make_float2(hx, hy);
}

// ---------------------------------------------------------------------------
// Kernel 3: apply — scan each chunk from hstart, overwrite u -> h in place.
// 2 d-chains per thread. Last chunk's thread also writes h_last.
// ---------------------------------------------------------------------------
__global__ __launch_bounds__(256) void scan_apply(
    const unsigned short* __restrict__ a, const float* __restrict__ hstart,
    float* __restrict__ out)
{
    int tid = blockIdx.x * 256 + threadIdx.x;
    int d = (tid & 511) << 1;
    int bc = tid >> 9;
    int b = bc >> 6;
    int c = bc & (NCHUNK - 1);
    size_t base = ((size_t)b * T_DIM + (size_t)c * CHUNK_L) * D_DIM + d;
    float2 h = *(const float2*)(hstart + bc * D_DIM + d);
    float hx = h.x, hy = h.y;
    #pragma unroll 4
    for (int t = 0; t < CHUNK_L; t++) {
        size_t idx = base + (size_t)t * D_DIM;
        unsigned ap = *(const unsigned*)(a + idx);
        float2 uv = *(const float2*)(out + idx);
        hx = unp_lo(ap) * hx + uv.x;
        hy = unp_hi(ap) * hy + uv.y;
        *(float2*)(out + idx) = make_float2(hx, hy);
    }
    if (c == NCHUNK - 1)
        *(float2*)(out + (size_t)M_DIM * D_DIM + b * D_DIM + d) = make_float2(hx, hy);
}

// ---------------------------------------------------------------------------
extern "C" void kernel_launch(void* const* d_in, const int* in_sizes, int n_in,
                              void* d_out, int out_size, void* d_ws, size_t ws_size,
                              hipStream_t stream)
{
    const float* x  = (const float*)d_in[0];
    const float* h0 = (const float*)d_in[1];
    const float* Wr = (const float*)d_in[2];
    const float* br = (const float*)d_in[3];
    const float* Wi = (const float*)d_in[4];
    const float* bi = (const float*)d_in[5];
    const float* Wx = (const float*)d_in[6];
    float* out = (float*)d_out;

    char* ws = (char*)d_ws;
    unsigned short* xb = (unsigned short*)ws;                          // 32 MB
    unsigned short* wb = (unsigned short*)(ws + 33554432);             // 6 MB
    unsigned short* a_buf = (unsigned short*)(ws + 33554432 + 6291456);// 32 MB bf16
    float* hstart = (float*)(ws + 33554432 + 6291456 + 33554432);      // 1 MB

    // 0: fp32 -> bf16 (x and the three weights)
    cvt_kernel<<<19456, 256, 0, stream>>>(x, Wr, Wi, Wx, xb, wb);
    // 1: 3-fused GEMM + gating (B direct-to-reg). a(bf16) -> ws, u -> d_out
    fused_gemm<<<1024, 512, 0, stream>>>(xb, wb, br, bi, a_buf, out);
    // 2: chunk-start h via warm-up (no sequential dependency)
    scan_warm<<<512, 256, 0, stream>>>(a_buf, out, h0, hstart);
    // 3: in-place chunk scan + h_last
    scan_apply<<<512, 256, 0, stream>>>(a_buf, hstart, out);
}

// Round 9
// 288.067 us; speedup vs baseline: 1.4163x; 1.4163x over previous
//
#include <hip/hip_runtime.h>
#include <stdint.h>

#define D_DIM 1024
#define T_DIM 4096
#define B_DIM 4
#define M_DIM 16384
#define NX 16777216UL
#define NW 1048576UL
#define LOG8F 2.0794415416798357f
#define CHUNK_L 64
#define NCHUNK 64
#define WARM 16
#define NT 32

typedef __attribute__((ext_vector_type(4))) float f32x4;
typedef __attribute__((ext_vector_type(8))) short bf16x8;

__device__ __forceinline__ unsigned short f2bf(float f) {
    unsigned u = __float_as_uint(f);
    u += 0x7fffu + ((u >> 16) & 1u);
    return (unsigned short)(u >> 16);
}
__device__ __forceinline__ float unp_lo(unsigned p) { return __uint_as_float(p << 16); }
__device__ __forceinline__ float unp_hi(unsigned p) { return __uint_as_float(p & 0xffff0000u); }
__device__ __forceinline__ float sigm(float x) { return 1.0f / (1.0f + __expf(-x)); }

__device__ __forceinline__ void gl_lds16(const void* g, void* l) {
    __builtin_amdgcn_global_load_lds(
        (const __attribute__((address_space(1))) void*)g,
        (__attribute__((address_space(3))) void*)l, 16, 0, 0);
}

// ---------------------------------------------------------------------------
// Kernel 0: convert x, W_r, W_i, W_x  fp32 -> bf16 (4 elems/thread)
// ---------------------------------------------------------------------------
__global__ __launch_bounds__(256) void cvt_kernel(
    const float* __restrict__ x, const float* __restrict__ Wr,
    const float* __restrict__ Wi, const float* __restrict__ Wx,
    unsigned short* __restrict__ xb, unsigned short* __restrict__ wb)
{
    size_t tid = (size_t)blockIdx.x * 256 + threadIdx.x;
    size_t i = tid * 4;
    const float* src;
    unsigned short* dst;
    size_t off;
    if (i < NX) {
        src = x; dst = xb; off = i;
    } else {
        size_t j = i - NX;
        size_t w = j >> 20;           // / NW
        off = j & (NW - 1);
        src = (w == 0) ? Wr : (w == 1 ? Wi : Wx);
        dst = wb + w * NW;
    }
    float4 v = *(const float4*)(src + off);
    ushort4 o;
    o.x = f2bf(v.x); o.y = f2bf(v.y); o.z = f2bf(v.z); o.w = f2bf(v.w);
    *(ushort4*)(dst + off) = o;
}

// ---------------------------------------------------------------------------
// Kernel 1: single-pass 3-fused GEMM + gating -- R5-VERIFIED body (142 us,
//   MfmaUtil 32%, 0 bank conflicts). R8 post-mortem: B direct-to-register
//   was 1.9x WORSE (270 us, MfmaUtil 15.6%) -- 16 scattered 64B lines per
//   load instruction serialize in the TCP/L1 and the 48 KB/tile B set
//   misses L1. LDS staging amortizes that; do not revisit.
//   Structure: x+3W in one K-loop, 8 waves, wave tile 64m x 32d x 3w,
//   BK=32, 4-deep LDS (128 KB), counted vmcnt(4) (stage(t+1) landed; 2
//   newer stages in flight across the barrier), fragment reg-dbuf,
//   XOR-swizzle (involution on both sides of gl_lds), setprio on MFMA,
//   bid&7 = d-tile = XCD keeps per-XCD W-slice L2-resident.
//   NEW (R9): epilogue also writes the 16 chunk-tail u rows per 64-chunk
//   (i==3 -> compile-time) to a compact wtail buffer so the scan can fuse
//   warm+apply into one launch without the in-place u hazard.
// ---------------------------------------------------------------------------
__global__ __launch_bounds__(512, 2) void fused_gemm(
    const unsigned short* __restrict__ xb, const unsigned short* __restrict__ wb,
    const float* __restrict__ b_r, const float* __restrict__ b_i,
    unsigned short* __restrict__ a_out, float* __restrict__ u_out,
    float* __restrict__ wtail)
{
    // per buffer: A[128][32] = 4096 ush (8 KB) then B[3][128][32] = 12288 ush
    __shared__ __align__(16) unsigned short lds[4][16384];   // 128 KB

    const int tid  = threadIdx.x;
    const int lane = tid & 63;
    const int wave = tid >> 6;
    const int wm = wave & 1;            // m-half (64 rows of 128)
    const int wn = wave >> 1;           // d-quarter (32 cols of 128)
    const int m0 = ((int)blockIdx.x >> 3) * 128;
    const int d0 = ((int)blockIdx.x & 7) * 128;
    const int frow = lane & 15;
    const int kgrp = lane >> 4;

    // staging: thread -> LDS slot (row=tid>>2, cg=tid&3); global source
    // col-group inverse-swizzled so swizzled ds_read returns correct data
    const int r0 = tid >> 2;            // 0..127
    const int cgs = (tid & 3) ^ ((r0 >> 1) & 3);
    const unsigned short* srcA  = xb + (size_t)(m0 + r0) * D_DIM + cgs * 8;
    const unsigned short* srcB0 = wb + (size_t)(d0 + r0) * D_DIM + cgs * 8;
    const unsigned short* srcB1 = srcB0 + NW;
    const unsigned short* srcB2 = srcB0 + 2 * NW;

    // reader offsets (ushort units, within one 16384-ush buffer), swizzled
    int offA[4], offB[3][2];
    #pragma unroll
    for (int i = 0; i < 4; i++) {
        const int row = wm * 64 + i * 16 + frow;
        offA[i] = row * 32 + ((kgrp ^ ((row >> 1) & 3)) << 3);
    }
    #pragma unroll
    for (int w = 0; w < 3; w++)
        #pragma unroll
        for (int j = 0; j < 2; j++) {
            const int row = wn * 32 + j * 16 + frow;
            offB[w][j] = (1 + w) * 4096 + row * 32 + ((kgrp ^ ((row >> 1) & 3)) << 3);
        }

    f32x4 acc[3][4][2];
    #pragma unroll
    for (int w = 0; w < 3; w++)
        #pragma unroll
        for (int i = 0; i < 4; i++)
            #pragma unroll
            for (int j = 0; j < 2; j++) acc[w][i][j] = (f32x4){0.f, 0.f, 0.f, 0.f};

    auto stage = [&](int t) {
        const int buf = t & 3;
        const int k0 = t << 5;
        gl_lds16(srcA  + k0, &lds[buf][tid * 8]);
        gl_lds16(srcB0 + k0, &lds[buf][4096 + tid * 8]);
        gl_lds16(srcB1 + k0, &lds[buf][8192 + tid * 8]);
        gl_lds16(srcB2 + k0, &lds[buf][12288 + tid * 8]);
    };

    // double-buffered fragments (explicit names -- rule 20: static indexing)
    bf16x8 af_a[4], af_b[4], bf_a[3][2], bf_b[3][2];

    stage(0); stage(1); stage(2);
    asm volatile("s_waitcnt vmcnt(8)" ::: "memory");   // stage(0) landed
    __builtin_amdgcn_s_barrier();
    asm volatile("" ::: "memory");
    #pragma unroll
    for (int i = 0; i < 4; i++) af_a[i] = *(const bf16x8*)&lds[0][offA[i]];
    #pragma unroll
    for (int w = 0; w < 3; w++)
        #pragma unroll
        for (int j = 0; j < 2; j++) bf_a[w][j] = *(const bf16x8*)&lds[0][offB[w][j]];

// STEP(T): vmcnt(VM) guarantees stage(T+1) landed (steady state: 3 tiles in
// flight, outstanding allowed = stage(T+2)'s 4 loads). Barrier publishes
// tile T+1. Then: prefetch-issue stage(T+3), ds_read tile T+1's fragments
// into the NXT bank, and run tile T's 24 MFMAs from the CUR bank -- reads
// and MFMAs are register-independent, so they interleave on the two pipes.
#define STEP(T, AFC, BFC, AFN, BFN, VM)                                       \
    {                                                                         \
        asm volatile("s_waitcnt vmcnt(" #VM ")" ::: "memory");                \
        __builtin_amdgcn_s_barrier();                                         \
        asm volatile("" ::: "memory");                                        \
        if ((T) + 3 < NT) stage((T) + 3);                                     \
        if ((T) + 1 < NT) {                                                   \
            const unsigned short* nb = lds[((T) + 1) & 3];                    \
            _Pragma("unroll")                                                 \
            for (int i = 0; i < 4; i++)                                       \
                AFN[i] = *(const bf16x8*)&nb[offA[i]];                        \
            _Pragma("unroll")                                                 \
            for (int w = 0; w < 3; w++)                                       \
                _Pragma("unroll")                                             \
                for (int j = 0; j < 2; j++)                                   \
                    BFN[w][j] = *(const bf16x8*)&nb[offB[w][j]];              \
        }                                                                     \
        __builtin_amdgcn_s_setprio(1);                                        \
        _Pragma("unroll")                                                     \
        for (int w = 0; w < 3; w++)                                           \
            _Pragma("unroll")                                                 \
            for (int i = 0; i < 4; i++)                                       \
                _Pragma("unroll")                                             \
                for (int j = 0; j < 2; j++)                                   \
                    acc[w][i][j] = __builtin_amdgcn_mfma_f32_16x16x32_bf16(   \
                        AFC[i], BFC[w][j], acc[w][i][j], 0, 0, 0);            \
        __builtin_amdgcn_s_setprio(0);                                        \
    }

    for (int t = 0; t < 28; t += 2) {
        STEP(t,     af_a, bf_a, af_b, bf_b, 4);
        STEP(t + 1, af_b, bf_b, af_a, bf_a, 4);
    }
    STEP(28, af_a, bf_a, af_b, bf_b, 4);
    STEP(29, af_b, bf_b, af_a, bf_a, 4);
    STEP(30, af_a, bf_a, af_b, bf_b, 0);   // stage(31) is the last in flight
    STEP(31, af_b, bf_b, af_a, bf_a, 0);
#undef STEP

    // Epilogue. C/D layout: col(d) = lane&15, row(m) = (lane>>4)*4 + r.
    const int mb = m0 + wm * 64 + kgrp * 4;
    const int db = d0 + wn * 32 + frow;
    #pragma unroll
    for (int j = 0; j < 2; j++) {
        const int d = db + j * 16;
        const float br = b_r[d];
        const float bi = b_i[d];
        #pragma unroll
        for (int i = 0; i < 4; i++) {
            const int m = mb + i * 16;
            #pragma unroll
            for (int r = 0; r < 4; r++) {
                const int mr = m + r;
                const size_t idx = (size_t)mr * D_DIM + d;
                float rg = sigm(acc[0][i][j][r] + br);
                // exp(-softplus(z)) == sigmoid(-z);  a in (0.11, 0.5)
                float a = sigm(-LOG8F * rg);
                a_out[idx] = f2bf(a);
                float g = sqrtf(fmaxf(1.0f - a * a, 1e-6f));
                float uval = g * sigm(acc[1][i][j][r] + bi) * acc[2][i][j][r];
                u_out[idx] = uval;
                // chunk-tail copy for the fused scan's warm-up.
                // (mr&63)>=48 <=> i==3 here (kgrp*4+r <= 15).
                if (i == 3) {
                    const int t = mr & 4095;
                    if (t < 4032) {     // c_next <= 63
                        const int b = mr >> 12;
                        const size_t widx =
                            ((((size_t)b << 6) + ((t >> 6) + 1)) * WARM +
                             (t & 15)) * D_DIM + d;
                        wtail[widx] = uval;
                    }
                }
            }
        }
    }
}

// ---------------------------------------------------------------------------
// Kernel 2: FUSED scan (was scan_warm + scan_apply).
//   Warm-up u values come from the gemm-written wtail copy (never
//   overwritten), so the in-place apply no longer races the warm reads of
//   the previous chunk -- one launch, no hstart buffer, one fewer
//   inter-kernel bubble. a <= 0.5 => decay >= 1 bit/step, so 16-step
//   warm-up truncation error <= 2^-16 * |h|. 2 d-chains per thread.
// ---------------------------------------------------------------------------
__global__ __launch_bounds__(256) void scan_fused(
    const unsigned short* __restrict__ a, const float* __restrict__ wtail,
    const float* __restrict__ h0, float* __restrict__ out)
{
    int tid = blockIdx.x * 256 + threadIdx.x;   // (b*NCHUNK + c)*512 + d2
    int d = (tid & 511) << 1;
    int bc = tid >> 9;
    int b = bc >> 6;
    int c = bc & (NCHUNK - 1);
    float hx, hy;
    if (c == 0) {
        float2 h = *(const float2*)(h0 + b * D_DIM + d);
        hx = h.x; hy = h.y;
    } else {
        hx = 0.0f; hy = 0.0f;
        size_t abase = ((size_t)b * T_DIM + (size_t)c * CHUNK_L - WARM) * D_DIM + d;
        size_t wbase = ((size_t)bc * WARM) * D_DIM + d;
        #pragma unroll 4
        for (int t = 0; t < WARM; t++) {
            unsigned ap = *(const unsigned*)(a + abase + (size_t)t * D_DIM);
            float2 uv = *(const float2*)(wtail + wbase + (size_t)t * D_DIM);
            hx = unp_lo(ap) * hx + uv.x;
            hy = unp_hi(ap) * hy + uv.y;
        }
    }
    size_t base = ((size_t)b * T_DIM + (size_t)c * CHUNK_L) * D_DIM + d;
    #pragma unroll 4
    for (int t = 0; t < CHUNK_L; t++) {
        size_t idx = base + (size_t)t * D_DIM;
        unsigned ap = *(const unsigned*)(a + idx);
        float2 uv = *(const float2*)(out + idx);
        hx = unp_lo(ap) * hx + uv.x;
        hy = unp_hi(ap) * hy + uv.y;
        *(float2*)(out + idx) = make_float2(hx, hy);
    }
    if (c == NCHUNK - 1)
        *(float2*)(out + (size_t)M_DIM * D_DIM + b * D_DIM + d) = make_float2(hx, hy);
}

// ---------------------------------------------------------------------------
extern "C" void kernel_launch(void* const* d_in, const int* in_sizes, int n_in,
                              void* d_out, int out_size, void* d_ws, size_t ws_size,
                              hipStream_t stream)
{
    const float* x  = (const float*)d_in[0];
    const float* h0 = (const float*)d_in[1];
    const float* Wr = (const float*)d_in[2];
    const float* br = (const float*)d_in[3];
    const float* Wi = (const float*)d_in[4];
    const float* bi = (const float*)d_in[5];
    const float* Wx = (const float*)d_in[6];
    float* out = (float*)d_out;

    char* ws = (char*)d_ws;
    unsigned short* xb = (unsigned short*)ws;                          // 32 MB
    unsigned short* wb = (unsigned short*)(ws + 33554432);             // 6 MB
    unsigned short* a_buf = (unsigned short*)(ws + 33554432 + 6291456);// 32 MB bf16
    float* wtail = (float*)(ws + 33554432 + 6291456 + 33554432);       // 16 MB

    // 0: fp32 -> bf16 (x and the three weights)
    cvt_kernel<<<19456, 256, 0, stream>>>(x, Wr, Wi, Wx, xb, wb);
    // 1: 3-fused GEMM + gating. a(bf16) -> ws, u(fp32) -> d_out, tails -> ws
    fused_gemm<<<1024, 512, 0, stream>>>(xb, wb, br, bi, a_buf, out, wtail);
    // 2: fused warm-up + in-place chunk scan + h_last (single launch)
    scan_fused<<<512, 256, 0, stream>>>(a_buf, wtail, h0, out);
}

// Round 10
// 287.968 us; speedup vs baseline: 1.4168x; 1.0003x over previous
//
#include <hip/hip_runtime.h>
#include <stdint.h>

#define D_DIM 1024
#define T_DIM 4096
#define B_DIM 4
#define M_DIM 16384
#define NX 16777216UL
#define NW 1048576UL
#define NTOT 19922944UL
#define LOG8F 2.0794415416798357f
#define CHUNK_L 64
#define NCHUNK 64
#define WARM 16
#define NT 32

typedef __attribute__((ext_vector_type(4))) float f32x4;
typedef __attribute__((ext_vector_type(8))) short bf16x8;

__device__ __forceinline__ unsigned short f2bf(float f) {
    unsigned u = __float_as_uint(f);
    u += 0x7fffu + ((u >> 16) & 1u);
    return (unsigned short)(u >> 16);
}
__device__ __forceinline__ unsigned packbf2(float x, float y) {
    unsigned ux = __float_as_uint(x);
    ux = (ux + 0x7fffu + ((ux >> 16) & 1u)) >> 16;
    unsigned uy = __float_as_uint(y);
    uy = (uy + 0x7fffu + ((uy >> 16) & 1u)) & 0xffff0000u;
    return ux | uy;
}
__device__ __forceinline__ float bfu(unsigned short p) {
    return __uint_as_float((unsigned)p << 16);
}
__device__ __forceinline__ float sigm(float x) { return 1.0f / (1.0f + __expf(-x)); }

__device__ __forceinline__ void gl_lds16(const void* g, void* l) {
    __builtin_amdgcn_global_load_lds(
        (const __attribute__((address_space(1))) void*)g,
        (__attribute__((address_space(3))) void*)l, 16, 0, 0);
}

// ---------------------------------------------------------------------------
// Kernel 0: convert x, W_r, W_i, W_x  fp32 -> bf16.
//   R10: grid-stride at 2048 blocks (G11: was 19456 tiny blocks), 8 elems
//   per thread-iter, one packed 16-B store. NX and NW are multiples of 8,
//   so an 8-group never straddles a region boundary.
// ---------------------------------------------------------------------------
__global__ __launch_bounds__(256) void cvt_kernel(
    const float* __restrict__ x, const float* __restrict__ Wr,
    const float* __restrict__ Wi, const float* __restrict__ Wx,
    unsigned short* __restrict__ xb, unsigned short* __restrict__ wb)
{
    const size_t stride = (size_t)gridDim.x * 256 * 8;
    for (size_t i = ((size_t)blockIdx.x * 256 + threadIdx.x) * 8;
         i < NTOT; i += stride) {
        const float* src;
        unsigned short* dst;
        size_t off;
        if (i < NX) {
            src = x; dst = xb; off = i;
        } else {
            size_t j = i - NX;
            size_t w = j >> 20;           // / NW
            off = j & (NW - 1);
            src = (w == 0) ? Wr : (w == 1 ? Wi : Wx);
            dst = wb + w * NW;
        }
        float4 v0 = *(const float4*)(src + off);
        float4 v1 = *(const float4*)(src + off + 4);
        uint4 o;
        o.x = packbf2(v0.x, v0.y);
        o.y = packbf2(v0.z, v0.w);
        o.z = packbf2(v1.x, v1.y);
        o.w = packbf2(v1.z, v1.w);
        *(uint4*)(dst + off) = o;
    }
}

// ---------------------------------------------------------------------------
// Kernel 1: single-pass 3-fused GEMM + gating -- R5/R9-VERIFIED body
//   (143.6 us, MfmaUtil 31.5%, 0 bank conflicts). UNCHANGED from R9.
//   R8 proved B direct-to-register is 1.9x worse (TCP-serialized scattered
//   lines); R4 proved bigger wave tiles spill. This structure is the local
//   optimum of the LDS-staged family: x+3W one K-loop, 8 waves, wave tile
//   64m x 32d x 3w, BK=32, 4-deep LDS (128 KB), counted vmcnt(4), fragment
//   reg-dbuf, XOR-swizzle, setprio, bid&7 = d-tile = XCD (W L2-resident).
//   Epilogue writes chunk-tail u rows to wtail for the fused scan.
// ---------------------------------------------------------------------------
__global__ __launch_bounds__(512, 2) void fused_gemm(
    const unsigned short* __restrict__ xb, const unsigned short* __restrict__ wb,
    const float* __restrict__ b_r, const float* __restrict__ b_i,
    unsigned short* __restrict__ a_out, float* __restrict__ u_out,
    float* __restrict__ wtail)
{
    // per buffer: A[128][32] = 4096 ush (8 KB) then B[3][128][32] = 12288 ush
    __shared__ __align__(16) unsigned short lds[4][16384];   // 128 KB

    const int tid  = threadIdx.x;
    const int lane = tid & 63;
    const int wave = tid >> 6;
    const int wm = wave & 1;            // m-half (64 rows of 128)
    const int wn = wave >> 1;           // d-quarter (32 cols of 128)
    const int m0 = ((int)blockIdx.x >> 3) * 128;
    const int d0 = ((int)blockIdx.x & 7) * 128;
    const int frow = lane & 15;
    const int kgrp = lane >> 4;

    // staging: thread -> LDS slot (row=tid>>2, cg=tid&3); global source
    // col-group inverse-swizzled so swizzled ds_read returns correct data
    const int r0 = tid >> 2;            // 0..127
    const int cgs = (tid & 3) ^ ((r0 >> 1) & 3);
    const unsigned short* srcA  = xb + (size_t)(m0 + r0) * D_DIM + cgs * 8;
    const unsigned short* srcB0 = wb + (size_t)(d0 + r0) * D_DIM + cgs * 8;
    const unsigned short* srcB1 = srcB0 + NW;
    const unsigned short* srcB2 = srcB0 + 2 * NW;

    // reader offsets (ushort units, within one 16384-ush buffer), swizzled
    int offA[4], offB[3][2];
    #pragma unroll
    for (int i = 0; i < 4; i++) {
        const int row = wm * 64 + i * 16 + frow;
        offA[i] = row * 32 + ((kgrp ^ ((row >> 1) & 3)) << 3);
    }
    #pragma unroll
    for (int w = 0; w < 3; w++)
        #pragma unroll
        for (int j = 0; j < 2; j++) {
            const int row = wn * 32 + j * 16 + frow;
            offB[w][j] = (1 + w) * 4096 + row * 32 + ((kgrp ^ ((row >> 1) & 3)) << 3);
        }

    f32x4 acc[3][4][2];
    #pragma unroll
    for (int w = 0; w < 3; w++)
        #pragma unroll
        for (int i = 0; i < 4; i++)
            #pragma unroll
            for (int j = 0; j < 2; j++) acc[w][i][j] = (f32x4){0.f, 0.f, 0.f, 0.f};

    auto stage = [&](int t) {
        const int buf = t & 3;
        const int k0 = t << 5;
        gl_lds16(srcA  + k0, &lds[buf][tid * 8]);
        gl_lds16(srcB0 + k0, &lds[buf][4096 + tid * 8]);
        gl_lds16(srcB1 + k0, &lds[buf][8192 + tid * 8]);
        gl_lds16(srcB2 + k0, &lds[buf][12288 + tid * 8]);
    };

    // double-buffered fragments (explicit names -- rule 20: static indexing)
    bf16x8 af_a[4], af_b[4], bf_a[3][2], bf_b[3][2];

    stage(0); stage(1); stage(2);
    asm volatile("s_waitcnt vmcnt(8)" ::: "memory");   // stage(0) landed
    __builtin_amdgcn_s_barrier();
    asm volatile("" ::: "memory");
    #pragma unroll
    for (int i = 0; i < 4; i++) af_a[i] = *(const bf16x8*)&lds[0][offA[i]];
    #pragma unroll
    for (int w = 0; w < 3; w++)
        #pragma unroll
        for (int j = 0; j < 2; j++) bf_a[w][j] = *(const bf16x8*)&lds[0][offB[w][j]];

// STEP(T): vmcnt(VM) guarantees stage(T+1) landed (steady state: 3 tiles in
// flight, outstanding allowed = stage(T+2)'s 4 loads). Barrier publishes
// tile T+1. Then: prefetch-issue stage(T+3), ds_read tile T+1's fragments
// into the NXT bank, and run tile T's 24 MFMAs from the CUR bank.
#define STEP(T, AFC, BFC, AFN, BFN, VM)                                       \
    {                                                                         \
        asm volatile("s_waitcnt vmcnt(" #VM ")" ::: "memory");                \
        __builtin_amdgcn_s_barrier();                                         \
        asm volatile("" ::: "memory");                                        \
        if ((T) + 3 < NT) stage((T) + 3);                                     \
        if ((T) + 1 < NT) {                                                   \
            const unsigned short* nb = lds[((T) + 1) & 3];                    \
            _Pragma("unroll")                                                 \
            for (int i = 0; i < 4; i++)                                       \
                AFN[i] = *(const bf16x8*)&nb[offA[i]];                        \
            _Pragma("unroll")                                                 \
            for (int w = 0; w < 3; w++)                                       \
                _Pragma("unroll")                                             \
                for (int j = 0; j < 2; j++)                                   \
                    BFN[w][j] = *(const bf16x8*)&nb[offB[w][j]];              \
        }                                                                     \
        __builtin_amdgcn_s_setprio(1);                                        \
        _Pragma("unroll")                                                     \
        for (int w = 0; w < 3; w++)                                           \
            _Pragma("unroll")                                                 \
            for (int i = 0; i < 4; i++)                                       \
                _Pragma("unroll")                                             \
                for (int j = 0; j < 2; j++)                                   \
                    acc[w][i][j] = __builtin_amdgcn_mfma_f32_16x16x32_bf16(   \
                        AFC[i], BFC[w][j], acc[w][i][j], 0, 0, 0);            \
        __builtin_amdgcn_s_setprio(0);                                        \
    }

    for (int t = 0; t < 28; t += 2) {
        STEP(t,     af_a, bf_a, af_b, bf_b, 4);
        STEP(t + 1, af_b, bf_b, af_a, bf_a, 4);
    }
    STEP(28, af_a, bf_a, af_b, bf_b, 4);
    STEP(29, af_b, bf_b, af_a, bf_a, 4);
    STEP(30, af_a, bf_a, af_b, bf_b, 0);   // stage(31) is the last in flight
    STEP(31, af_b, bf_b, af_a, bf_a, 0);
#undef STEP

    // Epilogue. C/D layout: col(d) = lane&15, row(m) = (lane>>4)*4 + r.
    const int mb = m0 + wm * 64 + kgrp * 4;
    const int db = d0 + wn * 32 + frow;
    #pragma unroll
    for (int j = 0; j < 2; j++) {
        const int d = db + j * 16;
        const float br = b_r[d];
        const float bi = b_i[d];
        #pragma unroll
        for (int i = 0; i < 4; i++) {
            const int m = mb + i * 16;
            #pragma unroll
            for (int r = 0; r < 4; r++) {
                const int mr = m + r;
                const size_t idx = (size_t)mr * D_DIM + d;
                float rg = sigm(acc[0][i][j][r] + br);
                // exp(-softplus(z)) == sigmoid(-z);  a in (0.11, 0.5)
                float a = sigm(-LOG8F * rg);
                a_out[idx] = f2bf(a);
                float g = sqrtf(fmaxf(1.0f - a * a, 1e-6f));
                float uval = g * sigm(acc[1][i][j][r] + bi) * acc[2][i][j][r];
                u_out[idx] = uval;
                // chunk-tail copy for the fused scan's warm-up.
                // (mr&63)>=48 <=> i==3 here (kgrp*4+r <= 15).
                if (i == 3) {
                    const int t = mr & 4095;
                    if (t < 4032) {     // c_next <= 63
                        const int b = mr >> 12;
                        const size_t widx =
                            ((((size_t)b << 6) + ((t >> 6) + 1)) * WARM +
                             (t & 15)) * D_DIM + d;
                        wtail[widx] = uval;
                    }
                }
            }
        }
    }
}

// ---------------------------------------------------------------------------
// Kernel 2: FUSED scan -- R10 parallelism rework.
//   R9 post-mortem: fusing launches without cutting bytes was NULL; the
//   scan is latency/BW-bound. Was: 2 d-chains/thread, 8 waves/CU, ~4
//   outstanding loads -> ~9 B/cy/CU in flight, right at the required rate
//   (latency-bound). Now: ONE d-chain per thread (262144 threads,
//   16 waves/CU) + unroll 8 (loads address-independent -> up to 16
//   outstanding per wave). In-flight capacity ~48 KB/CU >> needed.
//   Warm-up u from gemm-written wtail (never overwritten; no in-place
//   hazard). a <= 0.5 => >=1 bit decay/step => 16-step warm-up error
//   <= 2^-16 |h|.
// ---------------------------------------------------------------------------
__global__ __launch_bounds__(256) void scan_fused(
    const unsigned short* __restrict__ a, const float* __restrict__ wtail,
    const float* __restrict__ h0, float* __restrict__ out)
{
    int tid = blockIdx.x * 256 + threadIdx.x;   // (b*NCHUNK + c)*1024 + d
    int d = tid & 1023;
    int bc = tid >> 10;
    int b = bc >> 6;
    int c = bc & (NCHUNK - 1);
    float h;
    if (c == 0) {
        h = h0[b * D_DIM + d];
    } else {
        h = 0.0f;
        size_t abase = ((size_t)b * T_DIM + (size_t)c * CHUNK_L - WARM) * D_DIM + d;
        size_t wbase = ((size_t)bc * WARM) * D_DIM + d;
        #pragma unroll 8
        for (int t = 0; t < WARM; t++) {
            float av = bfu(a[abase + (size_t)t * D_DIM]);
            float uv = wtail[wbase + (size_t)t * D_DIM];
            h = av * h + uv;
        }
    }
    size_t base = ((size_t)b * T_DIM + (size_t)c * CHUNK_L) * D_DIM + d;
    #pragma unroll 8
    for (int t = 0; t < CHUNK_L; t++) {
        size_t idx = base + (size_t)t * D_DIM;
        float av = bfu(a[idx]);
        float uv = out[idx];
        h = av * h + uv;
        out[idx] = h;
    }
    if (c == NCHUNK - 1)
        out[(size_t)M_DIM * D_DIM + b * D_DIM + d] = h;
}

// ---------------------------------------------------------------------------
extern "C" void kernel_launch(void* const* d_in, const int* in_sizes, int n_in,
                              void* d_out, int out_size, void* d_ws, size_t ws_size,
                              hipStream_t stream)
{
    const float* x  = (const float*)d_in[0];
    const float* h0 = (const float*)d_in[1];
    const float* Wr = (const float*)d_in[2];
    const float* br = (const float*)d_in[3];
    const float* Wi = (const float*)d_in[4];
    const float* bi = (const float*)d_in[5];
    const float* Wx = (const float*)d_in[6];
    float* out = (float*)d_out;

    char* ws = (char*)d_ws;
    unsigned short* xb = (unsigned short*)ws;                          // 32 MB
    unsigned short* wb = (unsigned short*)(ws + 33554432);             // 6 MB
    unsigned short* a_buf = (unsigned short*)(ws + 33554432 + 6291456);// 32 MB bf16
    float* wtail = (float*)(ws + 33554432 + 6291456 + 33554432);       // 16 MB

    // 0: fp32 -> bf16 (x and the three weights), grid-stride
    cvt_kernel<<<2048, 256, 0, stream>>>(x, Wr, Wi, Wx, xb, wb);
    // 1: 3-fused GEMM + gating. a(bf16) -> ws, u(fp32) -> d_out, tails -> ws
    fused_gemm<<<1024, 512, 0, stream>>>(xb, wb, br, bi, a_buf, out, wtail);
    // 2: fused warm-up + in-place chunk scan + h_last (1 d-chain/thread)
    scan_fused<<<1024, 256, 0, stream>>>(a_buf, wtail, h0, out);
}